// Round 24
// baseline (89.408 us; speedup 1.0000x reference)
//
#include <hip/hip_runtime.h>

#define N_NODES 100000
#define N_EDGES 300000
#define CAP 32
#define NPAIRS (N_NODES / 2)
#define NT 64
#define NTILES ((N_NODES + NT - 1) / NT)
#define PAD 129

__device__ __forceinline__ ushort f32_to_bf16(float f)
{
    uint32_t b = __float_as_uint(f);
    uint32_t r = (b + 0x7FFFu + ((b >> 16) & 1u)) >> 16;   // RNE
    return (ushort)r;
}
__device__ __forceinline__ float bf16_to_f32(ushort u)
{
    return __uint_as_float(((uint32_t)u) << 16);
}
__device__ __forceinline__ uint32_t pack_bf16x2(float lo, float hi)
{
    return (uint32_t)f32_to_bf16(lo) | ((uint32_t)f32_to_bf16(hi) << 16);
}

// ---------------------------------------------------------------------------
// K1: setup — zero cnt (0.4 MB) + prepack weight tables in one launch.
// ---------------------------------------------------------------------------
__global__ __launch_bounds__(256) void setup_kernel(
    int4* __restrict__ zbase,
    const float* __restrict__ nn2_w, const float* __restrict__ nn2_b,
    const float* __restrict__ root2, const float* __restrict__ fc1_w,
    float* __restrict__ Wt, float* __restrict__ Ft)
{
    int gid = blockIdx.x * 256 + threadIdx.x;
    if (gid < 25000) zbase[gid] = make_int4(0, 0, 0, 0);
    if (gid < 4096) {
        int i = gid >> 5, o = gid & 31;
        int ii = i & 31;
        float v;
        if (i < 32)      v = nn2_w[(ii * 32 + o) * 2];
        else if (i < 64) v = nn2_w[(ii * 32 + o) * 2 + 1];
        else if (i < 96) v = nn2_b[ii * 32 + o];
        else             v = root2[ii * 32 + o];
        Wt[i * 32 + o] = v;
    }
    if (gid < 1024) {
        int o = gid >> 5, j = gid & 31;
        Ft[o * 32 + j] = fc1_w[j * 32 + o];
    }
}

// ---------------------------------------------------------------------------
// K2: bucket scatter (R15-validated). Int atomic for slot index only.
// ---------------------------------------------------------------------------
__global__ __launch_bounds__(256) void scatter_kernel(
    const int* __restrict__ src, const int* __restrict__ dst,
    const float* __restrict__ ea,
    int* __restrict__ cnt, float4* __restrict__ slots)
{
    int e = blockIdx.x * 256 + threadIdx.x;
    if (e >= N_EDGES) return;
    int s = src[e], d = dst[e];
    float2 a = ((const float2*)ea)[e];
    int pos = atomicAdd(&cnt[d], 1);
    if (pos < CAP)
        slots[(size_t)d * CAP + pos] = make_float4(__int_as_float(s), a.x, a.y, 0.f);
}

// ---------------------------------------------------------------------------
// K3: layer-1 edge-parallel butterfly (R19 chain-shortened; bf16 h1 out).
// ---------------------------------------------------------------------------
__global__ __launch_bounds__(256) void layer1a_kernel(
    const float* __restrict__ x, const int* __restrict__ cnt,
    const float4* __restrict__ slots,
    const float* __restrict__ nn1_w, const float* __restrict__ nn1_b,
    const float* __restrict__ root1, const float* __restrict__ bias1,
    ushort* __restrict__ h1b)
{
    int t = threadIdx.x;
    int wv = t >> 6, lane = t & 63, o = lane & 31, hihalf = lane >> 5;
    int pair = blockIdx.x * 4 + wv;
    if (pair >= NPAIRS) return;
    int n = pair * 2 + hihalf;
    int c = min(cnt[n], CAP);                      // parallel with slot load
    float4 sl = slots[(size_t)n * CAP + o];        // unconditional, coalesced
    bool g = o < c;
    int s = g ? __float_as_int(sl.x) : 0;
    float2 xv = ((const float2*)x)[s];
    float u0 = g ? xv.x * sl.y : 0.f;
    float u1 = g ? xv.x * sl.z : 0.f;
    float u2 = g ? xv.y * sl.y : 0.f;
    float u3 = g ? xv.y * sl.z : 0.f;
    float u4 = g ? xv.x : 0.f;
    float u5 = g ? xv.y : 0.f;
    #pragma unroll
    for (int m = 1; m < 32; m <<= 1) {
        u0 += __shfl_xor(u0, m, 32);
        u1 += __shfl_xor(u1, m, 32);
        u2 += __shfl_xor(u2, m, 32);
        u3 += __shfl_xor(u3, m, 32);
        u4 += __shfl_xor(u4, m, 32);
        u5 += __shfl_xor(u5, m, 32);
    }
    float2 w0 = ((const float2*)nn1_w)[o];
    float2 w1 = ((const float2*)nn1_w)[32 + o];
    float2 xn = ((const float2*)x)[n];
    float agg = u0 * w0.x + u1 * w0.y + u2 * w1.x + u3 * w1.y
              + u4 * nn1_b[o] + u5 * nn1_b[32 + o];
    float h = agg + fmaf(xn.x, root1[o], fmaf(xn.y, root1[32 + o], bias1[o]));
    h1b[(size_t)n * 32 + o] = f32_to_bf16(fmaxf(h, 0.f));
}

// ---------------------------------------------------------------------------
// K4: layer-2 gather, 8-WIDE PEEL: 8 unconditional slot loads (two 64B
// lines, always in-bounds at CAP=32) + 8 masked h1-row gathers in flight.
// Covers c<=8 = 98.6% of nodes (Poisson-3) in one 2-hop round; kills the
// serial tail round that 17.6% of nodes paid at the old 4-wide peel.
// Accumulation order identical to R23 -> absmax bit-identical.
// ---------------------------------------------------------------------------
__global__ __launch_bounds__(256) void gather_uvw_kernel(
    const ushort* __restrict__ h1b, const int* __restrict__ cnt,
    const float4* __restrict__ slots, uint32_t* __restrict__ UVWb)
{
    int t = threadIdx.x, o = t & 31;
    int n = blockIdx.x * 8 + (t >> 5);
    if (n >= N_NODES) return;
    const float4* sb = slots + (size_t)n * CAP;
    int c = min(cnt[n], CAP);              // parallel with slot loads
    float4 s0 = sb[0], s1 = sb[1], s2 = sb[2], s3 = sb[3];
    float4 s4 = sb[4], s5 = sb[5], s6 = sb[6], s7 = sb[7];
    bool g0 = 0 < c, g1 = 1 < c, g2 = 2 < c, g3 = 3 < c;
    bool g4 = 4 < c, g5 = 5 < c, g6 = 6 < c, g7 = 7 < c;
    int i0 = g0 ? __float_as_int(s0.x) : 0;
    int i1 = g1 ? __float_as_int(s1.x) : 0;
    int i2 = g2 ? __float_as_int(s2.x) : 0;
    int i3 = g3 ? __float_as_int(s3.x) : 0;
    int i4 = g4 ? __float_as_int(s4.x) : 0;
    int i5 = g5 ? __float_as_int(s5.x) : 0;
    int i6 = g6 ? __float_as_int(s6.x) : 0;
    int i7 = g7 ? __float_as_int(s7.x) : 0;
    float v0 = bf16_to_f32(h1b[(size_t)i0 * 32 + o]);
    float v1 = bf16_to_f32(h1b[(size_t)i1 * 32 + o]);
    float v2 = bf16_to_f32(h1b[(size_t)i2 * 32 + o]);
    float v3 = bf16_to_f32(h1b[(size_t)i3 * 32 + o]);
    float v4 = bf16_to_f32(h1b[(size_t)i4 * 32 + o]);
    float v5 = bf16_to_f32(h1b[(size_t)i5 * 32 + o]);
    float v6 = bf16_to_f32(h1b[(size_t)i6 * 32 + o]);
    float v7 = bf16_to_f32(h1b[(size_t)i7 * 32 + o]);
    float U = 0.f, V = 0.f, W = 0.f;
    U = fmaf(g0 ? s0.y : 0.f, v0, U);
    U = fmaf(g1 ? s1.y : 0.f, v1, U);
    U = fmaf(g2 ? s2.y : 0.f, v2, U);
    U = fmaf(g3 ? s3.y : 0.f, v3, U);
    U = fmaf(g4 ? s4.y : 0.f, v4, U);
    U = fmaf(g5 ? s5.y : 0.f, v5, U);
    U = fmaf(g6 ? s6.y : 0.f, v6, U);
    U = fmaf(g7 ? s7.y : 0.f, v7, U);
    V = fmaf(g0 ? s0.z : 0.f, v0, V);
    V = fmaf(g1 ? s1.z : 0.f, v1, V);
    V = fmaf(g2 ? s2.z : 0.f, v2, V);
    V = fmaf(g3 ? s3.z : 0.f, v3, V);
    V = fmaf(g4 ? s4.z : 0.f, v4, V);
    V = fmaf(g5 ? s5.z : 0.f, v5, V);
    V = fmaf(g6 ? s6.z : 0.f, v6, V);
    V = fmaf(g7 ? s7.z : 0.f, v7, V);
    W = fmaf(g0 ? 1.f : 0.f, v0, W);
    W = fmaf(g1 ? 1.f : 0.f, v1, W);
    W = fmaf(g2 ? 1.f : 0.f, v2, W);
    W = fmaf(g3 ? 1.f : 0.f, v3, W);
    W = fmaf(g4 ? 1.f : 0.f, v4, W);
    W = fmaf(g5 ? 1.f : 0.f, v5, W);
    W = fmaf(g6 ? 1.f : 0.f, v6, W);
    W = fmaf(g7 ? 1.f : 0.f, v7, W);
    // tail: c > 8 (~1.2% of nodes)
    for (int j0 = 8; j0 < c; j0 += 4) {
        bool h1g = j0 + 1 < c, h2g = j0 + 2 < c, h3g = j0 + 3 < c;
        float4 t0 = sb[j0];
        float4 t1 = sb[j0 + 1];
        float4 t2 = sb[j0 + 2];
        float4 t3 = sb[j0 + 3];
        int k0 = __float_as_int(t0.x);
        int k1 = h1g ? __float_as_int(t1.x) : 0;
        int k2 = h2g ? __float_as_int(t2.x) : 0;
        int k3 = h3g ? __float_as_int(t3.x) : 0;
        float w0v = bf16_to_f32(h1b[(size_t)k0 * 32 + o]);
        float w1v = bf16_to_f32(h1b[(size_t)k1 * 32 + o]);
        float w2v = bf16_to_f32(h1b[(size_t)k2 * 32 + o]);
        float w3v = bf16_to_f32(h1b[(size_t)k3 * 32 + o]);
        U = fmaf(t0.y, w0v, U);
        U = fmaf(h1g ? t1.y : 0.f, w1v, U);
        U = fmaf(h2g ? t2.y : 0.f, w2v, U);
        U = fmaf(h3g ? t3.y : 0.f, w3v, U);
        V = fmaf(t0.z, w0v, V);
        V = fmaf(h1g ? t1.z : 0.f, w1v, V);
        V = fmaf(h2g ? t2.z : 0.f, w2v, V);
        V = fmaf(h3g ? t3.z : 0.f, w3v, V);
        W += w0v;
        W = fmaf(h1g ? 1.f : 0.f, w1v, W);
        W = fmaf(h2g ? 1.f : 0.f, w2v, W);
        W = fmaf(h3g ? 1.f : 0.f, w3v, W);
    }
    // bf16-pack via neighbor-lane exchange; even lanes write channel pairs.
    float Un = __shfl_xor(U, 1, 32);
    float Vn = __shfl_xor(V, 1, 32);
    float Wn = __shfl_xor(W, 1, 32);
    size_t b = (size_t)n * 48;
    if ((o & 1) == 0) {
        int p = o >> 1;
        UVWb[b + p]      = pack_bf16x2(U, Un);
        UVWb[b + 16 + p] = pack_bf16x2(V, Vn);
        UVWb[b + 32 + p] = pack_bf16x2(W, Wn);
    }
}

// ---------------------------------------------------------------------------
// K5: matvec + fc (R23 form). bf16 UVW + bf16 h1 tiles -> fp32 LDS.
// ---------------------------------------------------------------------------
__global__ __launch_bounds__(512, 6) void matvec_fc_kernel(
    const uint32_t* __restrict__ UVWb, const ushort* __restrict__ h1b,
    const float* __restrict__ Wt, const float* __restrict__ Ft,
    const float* __restrict__ bias2,
    const float* __restrict__ fc1_b, const float* __restrict__ fc2_w,
    const float* __restrict__ fc2_b, float* __restrict__ out)
{
    __shared__ float ld[NT][PAD];
    __shared__ float h2s[NT][33];
    float* psf = &ld[0][0];           // ps[8][NT] overlay (ld dead in phase C)

    int t = threadIdx.x;
    int wv = t >> 6;
    int wvu = __builtin_amdgcn_readfirstlane(wv);
    int lane = t & 63;
    int tb = blockIdx.x * NT;

    // ---- Copy phase: bf16 tiles -> fp32 LDS ----
    {
        const uint32_t* uv = UVWb + (size_t)tb * 48;   // 3072 uints
        #pragma unroll
        for (int it = 0; it < 6; ++it) {
            int idx = it * 512 + t;                    // 0..3071
            uint32_t p = uv[idx];
            int node = idx / 48, ch = (idx % 48) * 2;
            ld[node][ch]     = __uint_as_float((p & 0xFFFFu) << 16);
            ld[node][ch + 1] = __uint_as_float(p & 0xFFFF0000u);
        }
        const uint32_t* h1u = (const uint32_t*)(h1b + (size_t)tb * 32);
        #pragma unroll
        for (int it = 0; it < 2; ++it) {
            int idx = it * 512 + t;                    // 0..1023
            uint32_t p = h1u[idx];
            int node = idx >> 4, ch = (idx & 15) * 2;
            ld[node][96 + ch]     = __uint_as_float((p & 0xFFFFu) << 16);
            ld[node][96 + ch + 1] = __uint_as_float(p & 0xFFFF0000u);
        }
    }
    __syncthreads();

    // ---- Phase B: node-parallel matvec; wave wv -> channels 4wv..4wv+3 ----
    {
        int cb = 4 * wvu;
        float4 bb = *(const float4*)(bias2 + cb);
        float a0 = bb.x, a1 = bb.y, a2 = bb.z, a3 = bb.w;
        #pragma unroll 8
        for (int i = 0; i < 128; ++i) {
            float hv = ld[lane][i];
            float4 wA = *(const float4*)(Wt + i * 32 + cb);
            a0 = fmaf(hv, wA.x, a0); a1 = fmaf(hv, wA.y, a1);
            a2 = fmaf(hv, wA.z, a2); a3 = fmaf(hv, wA.w, a3);
        }
        h2s[lane][cb + 0] = fmaxf(a0, 0.f);
        h2s[lane][cb + 1] = fmaxf(a1, 0.f);
        h2s[lane][cb + 2] = fmaxf(a2, 0.f);
        h2s[lane][cb + 3] = fmaxf(a3, 0.f);
    }
    __syncthreads();

    // ---- Phase C: fc1 + fc2 partials (psf aliases ld) ----
    {
        int cb = 4 * wvu;
        float4 fb = *(const float4*)(fc1_b + cb);
        float z0 = fb.x, z1 = fb.y, z2 = fb.z, z3 = fb.w;
        #pragma unroll 8
        for (int i = 0; i < 32; ++i) {
            float hv = h2s[lane][i];
            float4 fA = *(const float4*)(Ft + i * 32 + cb);
            z0 = fmaf(hv, fA.x, z0); z1 = fmaf(hv, fA.y, z1);
            z2 = fmaf(hv, fA.z, z2); z3 = fmaf(hv, fA.w, z3);
        }
        float4 cw = *(const float4*)(fc2_w + cb);
        float po = fmaxf(z0, 0.f) * cw.x + fmaxf(z1, 0.f) * cw.y
                 + fmaxf(z2, 0.f) * cw.z + fmaxf(z3, 0.f) * cw.w;
        __syncthreads();              // ld fully read before overlay write
        psf[wv * NT + lane] = po;
    }
    __syncthreads();
    if (wv == 0) {
        int n = tb + lane;
        if (n < N_NODES) {
            float s = psf[lane]          + psf[NT + lane]
                    + psf[2 * NT + lane] + psf[3 * NT + lane]
                    + psf[4 * NT + lane] + psf[5 * NT + lane]
                    + psf[6 * NT + lane] + psf[7 * NT + lane];
            out[n] = s + fc2_b[0];
        }
    }
}

extern "C" void kernel_launch(void* const* d_in, const int* in_sizes, int n_in,
                              void* d_out, int out_size, void* d_ws, size_t ws_size,
                              hipStream_t stream) {
    const float* x      = (const float*)d_in[0];
    const int*   ei     = (const int*)d_in[1];
    const float* ea     = (const float*)d_in[2];
    const float* nn1_w  = (const float*)d_in[3];
    const float* nn1_b  = (const float*)d_in[4];
    const float* root1  = (const float*)d_in[5];
    const float* bias1  = (const float*)d_in[6];
    const float* nn2_w  = (const float*)d_in[7];
    const float* nn2_b  = (const float*)d_in[8];
    const float* root2  = (const float*)d_in[9];
    const float* bias2  = (const float*)d_in[10];
    const float* fc1_w  = (const float*)d_in[11];
    const float* fc1_b  = (const float*)d_in[12];
    const float* fc2_w  = (const float*)d_in[13];
    const float* fc2_b  = (const float*)d_in[14];
    float* out = (float*)d_out;

    float* ws = (float*)d_ws;
    int*      cnt   = (int*)ws;
    float4*   slots = (float4*)(ws + 262144);                 // 16B-aligned
    ushort*   h1b   = (ushort*)(ws + 262144 + (size_t)N_NODES * CAP * 4);
    uint32_t* UVWb  = (uint32_t*)(ws + 262144 + (size_t)N_NODES * CAP * 4
                                  + 1600000);                 // 100k*48 uints
    float*    Wt    = ws + 262144 + (size_t)N_NODES * CAP * 4 + 1600000
                      + 4800000;
    float*    Ft    = Wt + 4096;

    const int* src = ei;
    const int* dst = ei + N_EDGES;

    setup_kernel<<<98, 256, 0, stream>>>(
        (int4*)cnt, nn2_w, nn2_b, root2, fc1_w, Wt, Ft);
    scatter_kernel<<<(N_EDGES + 255) / 256, 256, 0, stream>>>(
        src, dst, ea, cnt, slots);
    layer1a_kernel<<<(NPAIRS + 3) / 4, 256, 0, stream>>>(
        x, cnt, slots, nn1_w, nn1_b, root1, bias1, h1b);
    gather_uvw_kernel<<<(N_NODES + 7) / 8, 256, 0, stream>>>(
        h1b, cnt, slots, UVWb);
    matvec_fc_kernel<<<NTILES, 512, 0, stream>>>(
        UVWb, h1b, Wt, Ft, bias2, fc1_b, fc2_w, fc2_b, out);
}

// Round 25
// 86.761 us; speedup vs baseline: 1.0305x; 1.0305x over previous
//
#include <hip/hip_runtime.h>

#define N_NODES 100000
#define N_EDGES 300000
#define CAP 32
#define NPAIRS (N_NODES / 2)
#define NT 64
#define NTILES ((N_NODES + NT - 1) / NT)
#define PAD 129

__device__ __forceinline__ ushort f32_to_bf16(float f)
{
    uint32_t b = __float_as_uint(f);
    uint32_t r = (b + 0x7FFFu + ((b >> 16) & 1u)) >> 16;   // RNE
    return (ushort)r;
}
__device__ __forceinline__ float bf16_to_f32(ushort u)
{
    return __uint_as_float(((uint32_t)u) << 16);
}
__device__ __forceinline__ uint32_t pack_bf16x2(float lo, float hi)
{
    return (uint32_t)f32_to_bf16(lo) | ((uint32_t)f32_to_bf16(hi) << 16);
}

// ---------------------------------------------------------------------------
// K1: setup — zero cnt (0.4 MB) + prepack weight tables in one launch.
// ---------------------------------------------------------------------------
__global__ __launch_bounds__(256) void setup_kernel(
    int4* __restrict__ zbase,
    const float* __restrict__ nn2_w, const float* __restrict__ nn2_b,
    const float* __restrict__ root2, const float* __restrict__ fc1_w,
    float* __restrict__ Wt, float* __restrict__ Ft)
{
    int gid = blockIdx.x * 256 + threadIdx.x;
    if (gid < 25000) zbase[gid] = make_int4(0, 0, 0, 0);
    if (gid < 4096) {
        int i = gid >> 5, o = gid & 31;
        int ii = i & 31;
        float v;
        if (i < 32)      v = nn2_w[(ii * 32 + o) * 2];
        else if (i < 64) v = nn2_w[(ii * 32 + o) * 2 + 1];
        else if (i < 96) v = nn2_b[ii * 32 + o];
        else             v = root2[ii * 32 + o];
        Wt[i * 32 + o] = v;
    }
    if (gid < 1024) {
        int o = gid >> 5, j = gid & 31;
        Ft[o * 32 + j] = fc1_w[j * 32 + o];
    }
}

// ---------------------------------------------------------------------------
// K2: bucket scatter (R15-validated). Int atomic for slot index only.
// ---------------------------------------------------------------------------
__global__ __launch_bounds__(256) void scatter_kernel(
    const int* __restrict__ src, const int* __restrict__ dst,
    const float* __restrict__ ea,
    int* __restrict__ cnt, float4* __restrict__ slots)
{
    int e = blockIdx.x * 256 + threadIdx.x;
    if (e >= N_EDGES) return;
    int s = src[e], d = dst[e];
    float2 a = ((const float2*)ea)[e];
    int pos = atomicAdd(&cnt[d], 1);
    if (pos < CAP)
        slots[(size_t)d * CAP + pos] = make_float4(__int_as_float(s), a.x, a.y, 0.f);
}

// ---------------------------------------------------------------------------
// K3: layer-1 edge-parallel butterfly (R19 chain-shortened; bf16 h1 out).
// ---------------------------------------------------------------------------
__global__ __launch_bounds__(256) void layer1a_kernel(
    const float* __restrict__ x, const int* __restrict__ cnt,
    const float4* __restrict__ slots,
    const float* __restrict__ nn1_w, const float* __restrict__ nn1_b,
    const float* __restrict__ root1, const float* __restrict__ bias1,
    ushort* __restrict__ h1b)
{
    int t = threadIdx.x;
    int wv = t >> 6, lane = t & 63, o = lane & 31, hihalf = lane >> 5;
    int pair = blockIdx.x * 4 + wv;
    if (pair >= NPAIRS) return;
    int n = pair * 2 + hihalf;
    int c = min(cnt[n], CAP);                      // parallel with slot load
    float4 sl = slots[(size_t)n * CAP + o];        // unconditional, coalesced
    bool g = o < c;
    int s = g ? __float_as_int(sl.x) : 0;
    float2 xv = ((const float2*)x)[s];
    float u0 = g ? xv.x * sl.y : 0.f;
    float u1 = g ? xv.x * sl.z : 0.f;
    float u2 = g ? xv.y * sl.y : 0.f;
    float u3 = g ? xv.y * sl.z : 0.f;
    float u4 = g ? xv.x : 0.f;
    float u5 = g ? xv.y : 0.f;
    #pragma unroll
    for (int m = 1; m < 32; m <<= 1) {
        u0 += __shfl_xor(u0, m, 32);
        u1 += __shfl_xor(u1, m, 32);
        u2 += __shfl_xor(u2, m, 32);
        u3 += __shfl_xor(u3, m, 32);
        u4 += __shfl_xor(u4, m, 32);
        u5 += __shfl_xor(u5, m, 32);
    }
    float2 w0 = ((const float2*)nn1_w)[o];
    float2 w1 = ((const float2*)nn1_w)[32 + o];
    float2 xn = ((const float2*)x)[n];
    float agg = u0 * w0.x + u1 * w0.y + u2 * w1.x + u3 * w1.y
              + u4 * nn1_b[o] + u5 * nn1_b[32 + o];
    float h = agg + fmaf(xn.x, root1[o], fmaf(xn.y, root1[32 + o], bias1[o]));
    h1b[(size_t)n * 32 + o] = f32_to_bf16(fmaxf(h, 0.f));
}

// ---------------------------------------------------------------------------
// K4: layer-2 gather (R23 optimum: 4-wide peel; bf16 h1 in, bf16 UVW out).
// ---------------------------------------------------------------------------
__global__ __launch_bounds__(256) void gather_uvw_kernel(
    const ushort* __restrict__ h1b, const int* __restrict__ cnt,
    const float4* __restrict__ slots, uint32_t* __restrict__ UVWb)
{
    int t = threadIdx.x, o = t & 31;
    int n = blockIdx.x * 8 + (t >> 5);
    if (n >= N_NODES) return;
    const float4* sb = slots + (size_t)n * CAP;
    int c = min(cnt[n], CAP);              // parallel with slot loads
    float4 s0 = sb[0];
    float4 s1 = sb[1];
    float4 s2 = sb[2];
    float4 s3 = sb[3];
    bool g0 = 0 < c, g1 = 1 < c, g2 = 2 < c, g3 = 3 < c;
    int i0 = g0 ? __float_as_int(s0.x) : 0;
    int i1 = g1 ? __float_as_int(s1.x) : 0;
    int i2 = g2 ? __float_as_int(s2.x) : 0;
    int i3 = g3 ? __float_as_int(s3.x) : 0;
    float v0 = bf16_to_f32(h1b[(size_t)i0 * 32 + o]);
    float v1 = bf16_to_f32(h1b[(size_t)i1 * 32 + o]);
    float v2 = bf16_to_f32(h1b[(size_t)i2 * 32 + o]);
    float v3 = bf16_to_f32(h1b[(size_t)i3 * 32 + o]);
    float U = 0.f, V = 0.f, W = 0.f;
    U = fmaf(g0 ? s0.y : 0.f, v0, U);
    U = fmaf(g1 ? s1.y : 0.f, v1, U);
    U = fmaf(g2 ? s2.y : 0.f, v2, U);
    U = fmaf(g3 ? s3.y : 0.f, v3, U);
    V = fmaf(g0 ? s0.z : 0.f, v0, V);
    V = fmaf(g1 ? s1.z : 0.f, v1, V);
    V = fmaf(g2 ? s2.z : 0.f, v2, V);
    V = fmaf(g3 ? s3.z : 0.f, v3, V);
    W = fmaf(g0 ? 1.f : 0.f, v0, W);
    W = fmaf(g1 ? 1.f : 0.f, v1, W);
    W = fmaf(g2 ? 1.f : 0.f, v2, W);
    W = fmaf(g3 ? 1.f : 0.f, v3, W);
    for (int j0 = 4; j0 < c; j0 += 4) {
        bool h1g = j0 + 1 < c, h2g = j0 + 2 < c, h3g = j0 + 3 < c;
        float4 t0 = sb[j0];
        float4 t1 = sb[j0 + 1];
        float4 t2 = sb[j0 + 2];
        float4 t3 = sb[j0 + 3];
        int k0 = __float_as_int(t0.x);
        int k1 = h1g ? __float_as_int(t1.x) : 0;
        int k2 = h2g ? __float_as_int(t2.x) : 0;
        int k3 = h3g ? __float_as_int(t3.x) : 0;
        float w0v = bf16_to_f32(h1b[(size_t)k0 * 32 + o]);
        float w1v = bf16_to_f32(h1b[(size_t)k1 * 32 + o]);
        float w2v = bf16_to_f32(h1b[(size_t)k2 * 32 + o]);
        float w3v = bf16_to_f32(h1b[(size_t)k3 * 32 + o]);
        U = fmaf(t0.y, w0v, U);
        U = fmaf(h1g ? t1.y : 0.f, w1v, U);
        U = fmaf(h2g ? t2.y : 0.f, w2v, U);
        U = fmaf(h3g ? t3.y : 0.f, w3v, U);
        V = fmaf(t0.z, w0v, V);
        V = fmaf(h1g ? t1.z : 0.f, w1v, V);
        V = fmaf(h2g ? t2.z : 0.f, w2v, V);
        V = fmaf(h3g ? t3.z : 0.f, w3v, V);
        W += w0v;
        W = fmaf(h1g ? 1.f : 0.f, w1v, W);
        W = fmaf(h2g ? 1.f : 0.f, w2v, W);
        W = fmaf(h3g ? 1.f : 0.f, w3v, W);
    }
    // bf16-pack: lane o holds (U,V,W) for channel o; exchange with o^1 so
    // even lanes hold channel pairs (o, o+1) and write 48 uint32 per node.
    float Un = __shfl_xor(U, 1, 32);
    float Vn = __shfl_xor(V, 1, 32);
    float Wn = __shfl_xor(W, 1, 32);
    size_t b = (size_t)n * 48;
    if ((o & 1) == 0) {
        int p = o >> 1;                    // pair index 0..15
        UVWb[b + p]      = pack_bf16x2(U, Un);
        UVWb[b + 16 + p] = pack_bf16x2(V, Vn);
        UVWb[b + 32 + p] = pack_bf16x2(W, Wn);
    }
}

// ---------------------------------------------------------------------------
// K5: matvec + fc. UVW tile bf16-packed (48 uint32/node) + bf16 h1 tile.
// ---------------------------------------------------------------------------
__global__ __launch_bounds__(512, 6) void matvec_fc_kernel(
    const uint32_t* __restrict__ UVWb, const ushort* __restrict__ h1b,
    const float* __restrict__ Wt, const float* __restrict__ Ft,
    const float* __restrict__ bias2,
    const float* __restrict__ fc1_b, const float* __restrict__ fc2_w,
    const float* __restrict__ fc2_b, float* __restrict__ out)
{
    __shared__ float ld[NT][PAD];
    __shared__ float h2s[NT][33];
    float* psf = &ld[0][0];           // ps[8][NT] overlay (ld dead in phase C)

    int t = threadIdx.x;
    int wv = t >> 6;
    int wvu = __builtin_amdgcn_readfirstlane(wv);
    int lane = t & 63;
    int tb = blockIdx.x * NT;

    // ---- Copy phase: bf16 tiles -> fp32 LDS ----
    {
        const uint32_t* uv = UVWb + (size_t)tb * 48;   // 3072 uints
        #pragma unroll
        for (int it = 0; it < 6; ++it) {
            int idx = it * 512 + t;                    // 0..3071
            uint32_t p = uv[idx];
            int node = idx / 48, ch = (idx % 48) * 2;
            ld[node][ch]     = __uint_as_float((p & 0xFFFFu) << 16);
            ld[node][ch + 1] = __uint_as_float(p & 0xFFFF0000u);
        }
        const uint32_t* h1u = (const uint32_t*)(h1b + (size_t)tb * 32);
        #pragma unroll
        for (int it = 0; it < 2; ++it) {
            int idx = it * 512 + t;                    // 0..1023
            uint32_t p = h1u[idx];
            int node = idx >> 4, ch = (idx & 15) * 2;
            ld[node][96 + ch]     = __uint_as_float((p & 0xFFFFu) << 16);
            ld[node][96 + ch + 1] = __uint_as_float(p & 0xFFFF0000u);
        }
    }
    __syncthreads();

    // ---- Phase B: node-parallel matvec; wave wv -> channels 4wv..4wv+3 ----
    {
        int cb = 4 * wvu;
        float4 bb = *(const float4*)(bias2 + cb);
        float a0 = bb.x, a1 = bb.y, a2 = bb.z, a3 = bb.w;
        #pragma unroll 8
        for (int i = 0; i < 128; ++i) {
            float hv = ld[lane][i];
            float4 wA = *(const float4*)(Wt + i * 32 + cb);
            a0 = fmaf(hv, wA.x, a0); a1 = fmaf(hv, wA.y, a1);
            a2 = fmaf(hv, wA.z, a2); a3 = fmaf(hv, wA.w, a3);
        }
        h2s[lane][cb + 0] = fmaxf(a0, 0.f);
        h2s[lane][cb + 1] = fmaxf(a1, 0.f);
        h2s[lane][cb + 2] = fmaxf(a2, 0.f);
        h2s[lane][cb + 3] = fmaxf(a3, 0.f);
    }
    __syncthreads();

    // ---- Phase C: fc1 + fc2 partials (psf aliases ld) ----
    {
        int cb = 4 * wvu;
        float4 fb = *(const float4*)(fc1_b + cb);
        float z0 = fb.x, z1 = fb.y, z2 = fb.z, z3 = fb.w;
        #pragma unroll 8
        for (int i = 0; i < 32; ++i) {
            float hv = h2s[lane][i];
            float4 fA = *(const float4*)(Ft + i * 32 + cb);
            z0 = fmaf(hv, fA.x, z0); z1 = fmaf(hv, fA.y, z1);
            z2 = fmaf(hv, fA.z, z2); z3 = fmaf(hv, fA.w, z3);
        }
        float4 cw = *(const float4*)(fc2_w + cb);
        float po = fmaxf(z0, 0.f) * cw.x + fmaxf(z1, 0.f) * cw.y
                 + fmaxf(z2, 0.f) * cw.z + fmaxf(z3, 0.f) * cw.w;
        __syncthreads();              // ld fully read before overlay write
        psf[wv * NT + lane] = po;
    }
    __syncthreads();
    if (wv == 0) {
        int n = tb + lane;
        if (n < N_NODES) {
            float s = psf[lane]          + psf[NT + lane]
                    + psf[2 * NT + lane] + psf[3 * NT + lane]
                    + psf[4 * NT + lane] + psf[5 * NT + lane]
                    + psf[6 * NT + lane] + psf[7 * NT + lane];
            out[n] = s + fc2_b[0];
        }
    }
}

extern "C" void kernel_launch(void* const* d_in, const int* in_sizes, int n_in,
                              void* d_out, int out_size, void* d_ws, size_t ws_size,
                              hipStream_t stream) {
    const float* x      = (const float*)d_in[0];
    const int*   ei     = (const int*)d_in[1];
    const float* ea     = (const float*)d_in[2];
    const float* nn1_w  = (const float*)d_in[3];
    const float* nn1_b  = (const float*)d_in[4];
    const float* root1  = (const float*)d_in[5];
    const float* bias1  = (const float*)d_in[6];
    const float* nn2_w  = (const float*)d_in[7];
    const float* nn2_b  = (const float*)d_in[8];
    const float* root2  = (const float*)d_in[9];
    const float* bias2  = (const float*)d_in[10];
    const float* fc1_w  = (const float*)d_in[11];
    const float* fc1_b  = (const float*)d_in[12];
    const float* fc2_w  = (const float*)d_in[13];
    const float* fc2_b  = (const float*)d_in[14];
    float* out = (float*)d_out;

    float* ws = (float*)d_ws;
    int*      cnt   = (int*)ws;
    float4*   slots = (float4*)(ws + 262144);                 // 16B-aligned
    ushort*   h1b   = (ushort*)(ws + 262144 + (size_t)N_NODES * CAP * 4);
    uint32_t* UVWb  = (uint32_t*)(ws + 262144 + (size_t)N_NODES * CAP * 4
                                  + 1600000);                 // 100k*48 uints
    float*    Wt    = ws + 262144 + (size_t)N_NODES * CAP * 4 + 1600000
                      + 4800000;
    float*    Ft    = Wt + 4096;

    const int* src = ei;
    const int* dst = ei + N_EDGES;

    setup_kernel<<<98, 256, 0, stream>>>(
        (int4*)cnt, nn2_w, nn2_b, root2, fc1_w, Wt, Ft);
    scatter_kernel<<<(N_EDGES + 255) / 256, 256, 0, stream>>>(
        src, dst, ea, cnt, slots);
    layer1a_kernel<<<(NPAIRS + 3) / 4, 256, 0, stream>>>(
        x, cnt, slots, nn1_w, nn1_b, root1, bias1, h1b);
    gather_uvw_kernel<<<(N_NODES + 7) / 8, 256, 0, stream>>>(
        h1b, cnt, slots, UVWb);
    matvec_fc_kernel<<<NTILES, 512, 0, stream>>>(
        UVWb, h1b, Wt, Ft, bias2, fc1_b, fc2_w, fc2_b, out);
}